// Round 3
// baseline (422.580 us; speedup 1.0000x reference)
//
#include <hip/hip_runtime.h>

#define B_   4
#define C_   256
#define C2_  128
#define HIN  128
#define HO   63
#define NSEQ 3969          // 63*63
#define NPAD 4032          // 63*64
#define QPAD 4096          // 32 q-tiles of 128
#define D_   128
#define TOT  (B_*C_*NSEQ)  // 4064256
#define SPLITS 4

typedef _Float16 f16x8 __attribute__((ext_vector_type(8)));
typedef short    s16x8 __attribute__((ext_vector_type(8)));
typedef float    f32x4 __attribute__((ext_vector_type(4)));
typedef unsigned short u16;
typedef u16 u16x8 __attribute__((ext_vector_type(8)));

#define MFMA16(a,b,c) __builtin_amdgcn_mfma_f32_16x16x32_f16((a),(b),(c),0,0,0)
#define MFMABF(a,b,c) __builtin_amdgcn_mfma_f32_16x16x32_bf16((a),(b),(c),0,0,0)

__device__ __forceinline__ float b2f(u16 u) {
  unsigned v = ((unsigned)u) << 16;
  return __builtin_bit_cast(float, v);
}
__device__ __forceinline__ u16 f2b(float f) {
  unsigned u = __builtin_bit_cast(unsigned, f);
  return (u16)((u + 0x7FFFu + ((u >> 16) & 1u)) >> 16);
}

// DPP cross-lane reduction within 16-lane rows (no LDS traffic)
template<int CTRL>
__device__ __forceinline__ float dppf(float x) {
  return __builtin_bit_cast(float,
      __builtin_amdgcn_mov_dpp(__builtin_bit_cast(int, x), CTRL, 0xF, 0xF, true));
}
__device__ __forceinline__ float rmax16(float x) {
  x = fmaxf(x, dppf<0xB1>(x));    // quad_perm xor1
  x = fmaxf(x, dppf<0x4E>(x));    // quad_perm xor2
  x = fmaxf(x, dppf<0x124>(x));   // row_ror:4
  x = fmaxf(x, dppf<0x128>(x));   // row_ror:8
  return x;
}
__device__ __forceinline__ float rsum16(float x) {
  x += dppf<0xB1>(x);
  x += dppf<0x4E>(x);
  x += dppf<0x124>(x);
  x += dppf<0x128>(x);
  return x;
}

// ---------------- dtype detector ----------------
__global__ void detect_k(const void* x, int* flag) {
  __shared__ int cnt;
  if (threadIdx.x == 0) cnt = 0;
  __syncthreads();
  const u16* u = (const u16*)x;
  int c = 0;
  for (int i = threadIdx.x; i < 4096; i += 256) {
    int e = (u[i] >> 7) & 0xFF;
    if (e > 141) c++;
  }
  atomicAdd(&cnt, c);
  __syncthreads();
  if (threadIdx.x == 0) flag[0] = (cnt > 64) ? 0 : 1;  // 1 = bf16
}

// ---------------- maxpool 3x3 stride 2 -> xp[bc][NPAD], 4 outputs/thread ----------------
template<bool BF>
__device__ void maxpool_body(const void* x, void* xp) {
  int idx = blockIdx.x * 256 + threadIdx.x;   // B*C*HO*16 = 1032192 exact
  int w0 = (idx & 15) * 4;
  int hbc = idx >> 4;
  int h = hbc % HO, bc = hbc / HO;
  long base = ((long)bc * HIN + 2 * h) * HIN + 2 * w0;
  float best[4] = {-3e38f, -3e38f, -3e38f, -3e38f};
#pragma unroll
  for (int dh = 0; dh < 3; dh++) {
    long ro = base + dh * HIN;
    float c[9];
    if (BF) {
      u16x8 a = *(const u16x8*)((const u16*)x + ro);
      u16 b8 = ((const u16*)x)[ro + 8];
#pragma unroll
      for (int j = 0; j < 8; j++) c[j] = b2f(a[j]);
      c[8] = b2f(b8);
    } else {
      f32x4 a0 = *(const f32x4*)((const float*)x + ro);
      f32x4 a1 = *(const f32x4*)((const float*)x + ro + 4);
#pragma unroll
      for (int j = 0; j < 4; j++) { c[j] = a0[j]; c[4 + j] = a1[j]; }
      c[8] = ((const float*)x)[ro + 8];
    }
#pragma unroll
    for (int j = 0; j < 4; j++)
      best[j] = fmaxf(best[j], fmaxf(fmaxf(c[2 * j], c[2 * j + 1]), c[2 * j + 2]));
  }
#pragma unroll
  for (int j = 0; j < 4; j++) {
    int w = w0 + j;
    if (w < HO) {
      long o = (long)bc * NPAD + h * HO + w;
      if (BF) ((u16*)xp)[o] = f2b(best[j]);
      else    ((float*)xp)[o] = best[j];
    }
  }
}
__global__ __launch_bounds__(256) void maxpool_k(const void* x, void* xp, const int* flag) {
  if (flag[0]) maxpool_body<true>(x, xp); else maxpool_body<false>(x, xp);
}

// ---------------- xp (c,p) -> xpT (p,c), bf16 ----------------
__global__ __launch_bounds__(256) void transpose_k(const u16* xp, u16* xpT, const int* flag) {
  if (!flag[0]) return;
  __shared__ unsigned T32[64][33];
  int pt = blockIdx.x, cg = blockIdx.y, b = blockIdx.z;
  int tid = threadIdx.x;
  const u16* src = xp + ((long)(b * C_ + cg * 64)) * NPAD + pt * 64;
#pragma unroll
  for (int i = 0; i < 2; i++) {
    int c = (tid >> 3) + i * 32, p8 = (tid & 7) * 8;
    u16x8 v = *(const u16x8*)(src + (long)c * NPAD + p8);
#pragma unroll
    for (int j = 0; j < 4; j++)
      T32[c][(p8 >> 1) + j] = (unsigned)v[2 * j] | ((unsigned)v[2 * j + 1] << 16);
  }
  __syncthreads();
  u16* dst = xpT + ((long)b * NPAD + pt * 64) * C_ + cg * 64;
#pragma unroll
  for (int i = 0; i < 2; i++) {
    int p = (tid >> 3) + i * 32, c8 = (tid & 7) * 8;
    if (pt * 64 + p >= NSEQ) continue;
    u16x8 v;
#pragma unroll
    for (int j = 0; j < 8; j++) {
      unsigned wrd = T32[c8 + j][p >> 1];
      v[j] = (u16)((p & 1) ? (wrd >> 16) : wrd);
    }
    *(u16x8*)(dst + (long)p * C_ + c8) = v;
  }
}

// ---------------- QKV via exact bf16 MFMA, single-shot LDS ----------------
// Q layout: [b][QPAD][128] f16 (hi in Qh, lo in Ql). K: [b][NPAD][128] f16.
// V: [b][128][NPAD] f16 (V^T).
__global__ __launch_bounds__(256) void qkv_mfma_k(
    const u16* __restrict__ xpT, const void* tw, const void* pw, const void* gw,
    _Float16* Qh, _Float16* Ql, _Float16* Kv, _Float16* Vt, const int* flag) {
  if (!flag[0]) return;
  __shared__ u16 Asm[64 * 256];        // 32 KB, XOR-swizzled 16B chunks
  __shared__ u16 Bsm[64 * 256];        // 32 KB
  __shared__ float Tsm[4][16][64];     // 16 KB
  int pt = blockIdx.x, y = blockIdx.y, b = blockIdx.z;
  int tid = threadIdx.x, wave = tid >> 6, lane = tid & 63;
  int quad = lane >> 4, l16 = lane & 15;
  int mat = y >> 1, half = y & 1;
  const u16* W  = (const u16*)((mat == 0) ? tw : (mat == 1) ? pw : gw);
  const u16* Wr = W + (long)(half * 64) * C_;
  const u16* Xb = xpT + ((long)b * NPAD + pt * 64) * C_;
#pragma unroll
  for (int i = 0; i < 8; i++) {
    int g = tid + i * 256;             // 0..2047
    int r = g >> 5, cc = g & 31;
    int sw = (cc ^ (r & 15)) << 3;
    *(u16x8*)&Asm[r * 256 + sw] = *(const u16x8*)(Wr + (long)r * C_ + cc * 8);
    *(u16x8*)&Bsm[r * 256 + sw] = *(const u16x8*)(Xb + (long)r * C_ + cc * 8);
  }
  __syncthreads();
  f32x4 acc[4];
#pragma unroll
  for (int s = 0; s < 4; s++) acc[s] = (f32x4){0.f, 0.f, 0.f, 0.f};
#pragma unroll
  for (int kc = 0; kc < 8; kc++) {
    s16x8 a = *(const s16x8*)&Asm[(wave * 16 + l16) * 256 + (((kc * 4 + quad) ^ l16) << 3)];
#pragma unroll
    for (int s = 0; s < 4; s++) {
      s16x8 bf = *(const s16x8*)&Bsm[(s * 16 + l16) * 256 + (((kc * 4 + quad) ^ l16) << 3)];
      acc[s] = MFMABF(a, bf, acc[s]);
    }
  }
  int chanb = half * 64 + wave * 16;
  if (mat == 2) {
    _Float16* dv = Vt + (long)b * C2_ * NPAD;
#pragma unroll
    for (int s = 0; s < 4; s++)
#pragma unroll
      for (int r = 0; r < 4; r++) {
        int p = pt * 64 + s * 16 + l16;
        if (p < NSEQ) dv[(long)(chanb + quad * 4 + r) * NPAD + p] = (_Float16)acc[s][r];
      }
  } else {
#pragma unroll
    for (int s = 0; s < 4; s++)
#pragma unroll
      for (int r = 0; r < 4; r++)
        Tsm[wave][quad * 4 + r][s * 16 + l16] = acc[s][r];
    int p = pt * 64 + lane;            // same-wave LDS roundtrip, no barrier
    if (p < NSEQ) {
      f16x8 hv[2], lv[2];
#pragma unroll
      for (int cl = 0; cl < 16; cl++) {
        float v = Tsm[wave][cl][lane];
        _Float16 hx = (_Float16)v;
        hv[cl >> 3][cl & 7] = hx;
        lv[cl >> 3][cl & 7] = (_Float16)(v - (float)hx);
      }
      if (mat == 0) {
        _Float16* dh = Qh + (long)b * QPAD * 128 + (long)p * 128 + chanb;
        _Float16* dl = Ql + (long)b * QPAD * 128 + (long)p * 128 + chanb;
        *(f16x8*)dh = hv[0]; *(f16x8*)(dh + 8) = hv[1];
        *(f16x8*)dl = lv[0]; *(f16x8*)(dl + 8) = lv[1];
      } else {
        _Float16* dk = Kv + (long)b * NPAD * 128 + (long)p * 128 + chanb;
        *(f16x8*)dk = hv[0]; *(f16x8*)(dk + 8) = hv[1];
      }
    }
  }
}

// ---------------- QKV fp32 vector fallback ----------------
__global__ __launch_bounds__(256) void qkv_vec_k(
    const float* __restrict__ xp, const void* tw, const void* pw, const void* gw,
    _Float16* Qh, _Float16* Ql, _Float16* Kv, _Float16* Vt, const int* flag) {
  if (flag[0]) return;
  int b = blockIdx.z;
  int t = blockIdx.y >> 3, ot = blockIdx.y & 7;
  int pb = blockIdx.x, tid = threadIdx.x;
  const float* w = (const float*)((t == 0) ? tw : (t == 1) ? pw : gw);
  __shared__ float Wt[C_][16];
#pragma unroll
  for (int i = 0; i < 16; i++) {
    int g = tid + i * 256;
    int r = g >> 8, c = g & 255;
    Wt[c][r] = w[(ot * 16 + r) * C_ + c];
  }
  __syncthreads();
  int p0 = pb * 1024 + tid;
  const float* xb = xp + (long)b * C_ * NPAD;
  bool val[4];
#pragma unroll
  for (int j = 0; j < 4; j++) val[j] = (p0 + j * 256) < NSEQ;
  float acc[16][4];
#pragma unroll
  for (int r = 0; r < 16; r++)
#pragma unroll
    for (int j = 0; j < 4; j++) acc[r][j] = 0.f;
  for (int c = 0; c < C_; c++) {
    float xv[4];
#pragma unroll
    for (int j = 0; j < 4; j++) xv[j] = val[j] ? xb[(long)c * NPAD + p0 + j * 256] : 0.f;
#pragma unroll
    for (int r4 = 0; r4 < 4; r4++) {
      f32x4 w4 = *(const f32x4*)&Wt[c][r4 * 4];
#pragma unroll
      for (int rr = 0; rr < 4; rr++)
#pragma unroll
        for (int j = 0; j < 4; j++) acc[r4 * 4 + rr][j] += w4[rr] * xv[j];
    }
  }
  if (t < 2) {
#pragma unroll
    for (int j = 0; j < 4; j++) {
      if (!val[j]) continue;
      int p = p0 + j * 256;
      f16x8 hv[2], lv[2];
#pragma unroll
      for (int r = 0; r < 16; r++) {
        float a = acc[r][j];
        _Float16 h = (_Float16)a;
        hv[r >> 3][r & 7] = h;
        lv[r >> 3][r & 7] = (_Float16)(a - (float)h);
      }
      if (t == 0) {
        _Float16* dh = Qh + (long)b * QPAD * 128 + (long)p * 128 + ot * 16;
        _Float16* dl = Ql + (long)b * QPAD * 128 + (long)p * 128 + ot * 16;
        *(f16x8*)dh = hv[0]; *(f16x8*)(dh + 8) = hv[1];
        *(f16x8*)dl = lv[0]; *(f16x8*)(dl + 8) = lv[1];
      } else {
        _Float16* dk = Kv + (long)b * NPAD * 128 + (long)p * 128 + ot * 16;
        *(f16x8*)dk = hv[0]; *(f16x8*)(dk + 8) = hv[1];
      }
    }
  } else {
    _Float16* dv = Vt + (long)b * C2_ * NPAD;
#pragma unroll
    for (int r = 0; r < 16; r++)
#pragma unroll
      for (int j = 0; j < 4; j++) {
        int p = p0 + j * 256;
        if (val[j]) dv[(long)(ot * 16 + r) * NPAD + p] = (_Float16)acc[r][j];
      }
  }
}

// ---------------- flash attention v3 ----------------
// BM=128 (32 rows/wave), BN=64, 2-pass QK (Q hi/lo x K fp16), KV-split x4,
// XOR-swizzled LDS, 2 barriers/iter, register prefetch of next K/V tile.
__global__ __launch_bounds__(256, 2) void flash_k(
    const _Float16* __restrict__ Qh, const _Float16* __restrict__ Ql,
    const _Float16* __restrict__ Kv, const _Float16* __restrict__ Vt,
    float* __restrict__ Opart, float* __restrict__ Mp, float* __restrict__ Lp) {
  __shared__ _Float16 Ks[64 * 128];       // 16 KB, swizzled
  __shared__ _Float16 Vs[128 * 64];       // 16 KB, swizzled
  __shared__ _Float16 Ps[4][32 * 64];     // 16 KB, per-wave, swizzled

  int qt = blockIdx.x, split = blockIdx.y, b = blockIdx.z;
  int tid = threadIdx.x, wave = tid >> 6, lane = tid & 63;
  int quad = lane >> 4, l16 = lane & 15;

  const _Float16* Qhb = Qh + (long)b * QPAD * D_;
  const _Float16* Qlb = Ql + (long)b * QPAD * D_;
  const _Float16* Kb  = Kv + (long)b * NPAD * D_;
  const _Float16* Vb  = Vt + (long)b * C2_ * NPAD;

  int qr0 = qt * 128 + wave * 32;
  f16x8 aqh[2][4], aql[2][4];
#pragma unroll
  for (int h = 0; h < 2; h++) {
    long row = qr0 + h * 16 + l16;
#pragma unroll
    for (int kk = 0; kk < 4; kk++) {
      aqh[h][kk] = *(const f16x8*)(Qhb + row * D_ + kk * 32 + quad * 8);
      aql[h][kk] = *(const f16x8*)(Qlb + row * D_ + kk * 32 + quad * 8);
    }
  }

  f32x4 o_acc[2][8];
#pragma unroll
  for (int h = 0; h < 2; h++)
#pragma unroll
    for (int s = 0; s < 8; s++) o_acc[h][s] = (f32x4){0.f, 0.f, 0.f, 0.f};
  float m_r[2][4], l_r[2][4];
#pragma unroll
  for (int h = 0; h < 2; h++)
#pragma unroll
    for (int r = 0; r < 4; r++) { m_r[h][r] = -3e38f; l_r[h][r] = 0.f; }
  const float LOG2E = 1.4426950408889634f;

  int t0 = split * 16, t1 = min(63, t0 + 16);
  f16x8 kpf[4], vpf[4];
#pragma unroll
  for (int i = 0; i < 4; i++) {            // prefetch tile t0
    int g = tid + i * 256;
    kpf[i] = *(const f16x8*)(Kb + (long)(t0 * 64 + (g >> 4)) * D_ + (g & 15) * 8);
    vpf[i] = *(const f16x8*)(Vb + (long)(g >> 3) * NPAD + t0 * 64 + (g & 7) * 8);
  }

  for (int t = t0; t < t1; t++) {
    __syncthreads();                       // (A) prior readers of Ks/Vs done
#pragma unroll
    for (int i = 0; i < 4; i++) {
      int g = tid + i * 256;
      int r = g >> 4, cc = g & 15;
      *(f16x8*)&Ks[r * 128 + ((cc ^ (r & 15)) << 3)] = kpf[i];
      int c = g >> 3, c8 = g & 7;
      *(f16x8*)&Vs[c * 64 + ((c8 ^ (c & 7)) << 3)] = vpf[i];
    }
    __syncthreads();                       // (B) tiles visible
    if (t + 1 < t1) {
#pragma unroll
      for (int i = 0; i < 4; i++) {        // prefetch next tile during compute
        int g = tid + i * 256;
        kpf[i] = *(const f16x8*)(Kb + (long)((t + 1) * 64 + (g >> 4)) * D_ + (g & 15) * 8);
        vpf[i] = *(const f16x8*)(Vb + (long)(g >> 3) * NPAD + (t + 1) * 64 + (g & 7) * 8);
      }
    }

    f32x4 s_acc[2][4];
#pragma unroll
    for (int h = 0; h < 2; h++)
#pragma unroll
      for (int s = 0; s < 4; s++) s_acc[h][s] = (f32x4){0.f, 0.f, 0.f, 0.f};
#pragma unroll
    for (int kk = 0; kk < 4; kk++) {
#pragma unroll
      for (int s = 0; s < 4; s++) {
        f16x8 bh = *(const f16x8*)&Ks[(s * 16 + l16) * 128 + (((kk * 4 + quad) ^ l16) << 3)];
        s_acc[0][s] = MFMA16(aqh[0][kk], bh, s_acc[0][s]);
        s_acc[0][s] = MFMA16(aql[0][kk], bh, s_acc[0][s]);
        s_acc[1][s] = MFMA16(aqh[1][kk], bh, s_acc[1][s]);
        s_acc[1][s] = MFMA16(aql[1][kk], bh, s_acc[1][s]);
      }
    }
#pragma unroll
    for (int s = 0; s < 4; s++) {
      if (t * 64 + s * 16 + l16 >= NSEQ) {
#pragma unroll
        for (int h = 0; h < 2; h++)
#pragma unroll
          for (int r = 0; r < 4; r++) s_acc[h][s][r] = -3e38f;
      }
    }
#pragma unroll
    for (int h = 0; h < 2; h++) {
      float mx[4];
#pragma unroll
      for (int r = 0; r < 4; r++) {
        mx[r] = fmaxf(fmaxf(s_acc[h][0][r], s_acc[h][1][r]),
                      fmaxf(s_acc[h][2][r], s_acc[h][3][r]));
        mx[r] = rmax16(mx[r]);
      }
      float alpha[4];
#pragma unroll
      for (int r = 0; r < 4; r++) {
        float mn = fmaxf(m_r[h][r], mx[r]);
        alpha[r] = exp2f((m_r[h][r] - mn) * LOG2E);
        m_r[h][r] = mn;
      }
      float rs[4] = {0.f, 0.f, 0.f, 0.f};
      float pvv[4][4];
#pragma unroll
      for (int s = 0; s < 4; s++)
#pragma unroll
        for (int r = 0; r < 4; r++) {
          float p = exp2f((s_acc[h][s][r] - m_r[h][r]) * LOG2E);
          pvv[s][r] = p;
          rs[r] += p;
        }
#pragma unroll
      for (int r = 0; r < 4; r++) {
        rs[r] = rsum16(rs[r]);
        l_r[h][r] = l_r[h][r] * alpha[r] + rs[r];
      }
#pragma unroll
      for (int s8 = 0; s8 < 8; s8++)
#pragma unroll
        for (int r = 0; r < 4; r++) o_acc[h][s8][r] *= alpha[r];
      // P: C-layout -> per-wave swizzled LDS (no barrier needed)
#pragma unroll
      for (int s = 0; s < 4; s++)
#pragma unroll
        for (int r = 0; r < 4; r++) {
          int m = h * 16 + quad * 4 + r;
          Ps[wave][m * 64 + (((s * 2 + (l16 >> 3)) ^ (m & 7)) << 3) + (l16 & 7)] =
              (_Float16)pvv[s][r];
        }
    }
    f16x8 ap[2][2];
#pragma unroll
    for (int h = 0; h < 2; h++)
#pragma unroll
      for (int kk2 = 0; kk2 < 2; kk2++) {
        int m = h * 16 + l16;
        ap[h][kk2] = *(const f16x8*)&Ps[wave][m * 64 + (((kk2 * 4 + quad) ^ (m & 7)) << 3)];
      }
#pragma unroll
    for (int kk2 = 0; kk2 < 2; kk2++) {
#pragma unroll
      for (int s8 = 0; s8 < 8; s8++) {
        int c = s8 * 16 + l16;
        f16x8 bv = *(const f16x8*)&Vs[c * 64 + (((kk2 * 4 + quad) ^ (c & 7)) << 3)];
        o_acc[0][s8] = MFMA16(ap[0][kk2], bv, o_acc[0][s8]);
        o_acc[1][s8] = MFMA16(ap[1][kk2], bv, o_acc[1][s8]);
      }
    }
  }
  float* Ob = Opart + (long)(b * SPLITS + split) * NSEQ * D_;
  float* Mb = Mp + (long)(b * SPLITS + split) * NSEQ;
  float* Lb = Lp + (long)(b * SPLITS + split) * NSEQ;
#pragma unroll
  for (int h = 0; h < 2; h++)
#pragma unroll
    for (int r = 0; r < 4; r++) {
      int n = qt * 128 + wave * 32 + h * 16 + quad * 4 + r;
      if (n < NSEQ) {
#pragma unroll
        for (int s8 = 0; s8 < 8; s8++)
          Ob[(long)n * D_ + s8 * 16 + l16] = o_acc[h][s8][r];
        if (l16 == 0) { Mb[n] = m_r[h][r]; Lb[n] = l_r[h][r]; }
      }
    }
}

// ---------------- merge split partials ----------------
__global__ __launch_bounds__(256) void merge_k(const float* __restrict__ Opart,
                                               const float* __restrict__ Mp,
                                               const float* __restrict__ Lp,
                                               float* __restrict__ Y) {
  int row = blockIdx.x * 4 + (threadIdx.x >> 6);
  int lane = threadIdx.x & 63;
  int b = row / NSEQ, n = row - b * NSEQ;
  const float LOG2E = 1.4426950408889634f;
  float ms[SPLITS], m = -3e38f;
#pragma unroll
  for (int s = 0; s < SPLITS; s++) {
    ms[s] = Mp[(long)(b * SPLITS + s) * NSEQ + n];
    m = fmaxf(m, ms[s]);
  }
  float den = 0.f, a0 = 0.f, a1 = 0.f;
  int d = lane * 2;
#pragma unroll
  for (int s = 0; s < SPLITS; s++) {
    float w = exp2f((ms[s] - m) * LOG2E);
    den += Lp[(long)(b * SPLITS + s) * NSEQ + n] * w;
    const float* O = Opart + ((long)(b * SPLITS + s) * NSEQ + n) * D_ + d;
    a0 += w * O[0];
    a1 += w * O[1];
  }
  float inv = 1.f / den;
  float* Yo = Y + ((long)b * NSEQ + n) * D_ + d;
  Yo[0] = a0 * inv;
  Yo[1] = a1 * inv;
}

// ---------------- y_w GEMM on raw-viewed y + BN partial stats ----------------
template<bool BF>
__device__ void out_body(const float* __restrict__ Y, const void* yw, float* outp,
                         float* gsum, float* gsumsq) {
  int b = blockIdx.z, ot = blockIdx.y, pb = blockIdx.x, tid = threadIdx.x;
  __shared__ float Wt[C2_][16];
  __shared__ float red[2][16][4];
#pragma unroll
  for (int i = 0; i < 8; i++) {
    int g = tid + i * 256;
    int r = g >> 7, c = g & 127;
    Wt[c][r] = BF ? b2f(((const u16*)yw)[(ot * 16 + r) * C2_ + c])
                  : ((const float*)yw)[(ot * 16 + r) * C2_ + c];
  }
  __syncthreads();
  int p0 = pb * 1024 + tid;
  const float* Yb = Y + (long)b * NSEQ * D_;
  bool val[4];
#pragma unroll
  for (int j = 0; j < 4; j++) val[j] = (p0 + j * 256) < NSEQ;
  float acc[16][4];
#pragma unroll
  for (int r = 0; r < 16; r++)
#pragma unroll
    for (int j = 0; j < 4; j++) acc[r][j] = 0.f;
  for (int c = 0; c < C2_; c++) {
    float xv[4];
#pragma unroll
    for (int j = 0; j < 4; j++) xv[j] = val[j] ? Yb[(long)c * NSEQ + p0 + j * 256] : 0.f;
#pragma unroll
    for (int r4 = 0; r4 < 4; r4++) {
      f32x4 w4 = *(const f32x4*)&Wt[c][r4 * 4];
#pragma unroll
      for (int rr = 0; rr < 4; rr++)
#pragma unroll
        for (int j = 0; j < 4; j++) acc[r4 * 4 + rr][j] += w4[rr] * xv[j];
    }
  }
  long ob = ((long)b * C_ + ot * 16) * NSEQ;
#pragma unroll
  for (int r = 0; r < 16; r++)
#pragma unroll
    for (int j = 0; j < 4; j++)
      if (val[j]) outp[ob + (long)r * NSEQ + p0 + j * 256] = acc[r][j];
  int wave = tid >> 6, lane = tid & 63;
#pragma unroll
  for (int r = 0; r < 16; r++) {
    float s = 0.f, q = 0.f;
#pragma unroll
    for (int j = 0; j < 4; j++) { s += acc[r][j]; q += acc[r][j] * acc[r][j]; }
#pragma unroll
    for (int off = 1; off < 64; off <<= 1) {
      s += __shfl_xor(s, off, 64);
      q += __shfl_xor(q, off, 64);
    }
    if (lane == 0) { red[0][r][wave] = s; red[1][r][wave] = q; }
  }
  __syncthreads();
  if (tid < 32) {
    int which = tid >> 4, r = tid & 15;
    float v = red[which][r][0] + red[which][r][1] + red[which][r][2] + red[which][r][3];
    atomicAdd((which ? gsumsq : gsum) + ot * 16 + r, v);
  }
}
__global__ __launch_bounds__(256) void out_k(const float* Y, const void* yw, float* outp,
                                             float* gsum, float* gsumsq, const int* flag) {
  if (flag[0]) out_body<true>(Y, yw, outp, gsum, gsumsq);
  else         out_body<false>(Y, yw, outp, gsum, gsumsq);
}

// ---------------- BN (training) + residual + relu ----------------
template<bool BF>
__device__ void bn_body(const float* outp, const float* gsum, const float* gsumsq,
                        const void* bnw, const void* bnb, const void* xp, void* out) {
  int idx = blockIdx.x * 256 + threadIdx.x;
  if (idx >= TOT) return;
  int p = idx % NSEQ;
  int bc = idx / NSEQ;
  int c = bc & (C_ - 1);
  const float invn = 1.0f / (float)(B_ * NSEQ);
  float mean = gsum[c] * invn;
  float var = gsumsq[c] * invn - mean * mean;
  var = fmaxf(var, 0.f);
  float is = rsqrtf(var + 1e-5f);
  float w = BF ? b2f(((const u16*)bnw)[c]) : ((const float*)bnw)[c];
  float bb = BF ? b2f(((const u16*)bnb)[c]) : ((const float*)bnb)[c];
  float res = BF ? b2f(((const u16*)xp)[(long)bc * NPAD + p])
                 : ((const float*)xp)[(long)bc * NPAD + p];
  float v = (outp[idx] - mean) * is * w + bb + res;
  v = fmaxf(v, 0.f);
  if (BF) ((u16*)out)[idx] = f2b(v);
  else    ((float*)out)[idx] = v;
}
__global__ __launch_bounds__(256) void bn_k(const float* outp, const float* gsum, const float* gsumsq,
                                            const void* bnw, const void* bnb, const void* xp,
                                            void* out, const int* flag) {
  if (flag[0]) bn_body<true>(outp, gsum, gsumsq, bnw, bnb, xp, out);
  else         bn_body<false>(outp, gsum, gsumsq, bnw, bnb, xp, out);
}

// ---------------- launcher ----------------
extern "C" void kernel_launch(void* const* d_in, const int* in_sizes, int n_in,
                              void* d_out, int out_size, void* d_ws, size_t ws_size,
                              hipStream_t stream) {
  size_t off = 0;
  auto alloc = [&](size_t bytes) -> char* {
    char* p = (char*)d_ws + off;
    off += (bytes + 255) & ~(size_t)255;
    return p;
  };
  void*     xp   = alloc(sizeof(float) * (size_t)B_ * C_ * NPAD);          // 16.5 MB
  u16*      xpT  = (u16*)alloc(2 * (size_t)B_ * NPAD * C_);                // 8.3 MB
  _Float16* Qh   = (_Float16*)alloc(2 * (size_t)B_ * QPAD * D_);           // 4.2 MB
  _Float16* Ql   = (_Float16*)alloc(2 * (size_t)B_ * QPAD * D_);           // 4.2 MB
  _Float16* Kv   = (_Float16*)alloc(2 * (size_t)B_ * NPAD * D_);           // 4.1 MB
  _Float16* Vt   = (_Float16*)alloc(2 * (size_t)B_ * C2_ * NPAD);          // 4.1 MB
  float*    Yb   = (float*)alloc(sizeof(float) * (size_t)B_ * NSEQ * D_);  // 8.1 MB
  // big region: Opart (32.5 MB) during flash/merge, then outp (16.3 MB)
  float*    big  = (float*)alloc(sizeof(float) * (size_t)B_ * SPLITS * NSEQ * D_);
  float*    Mp   = (float*)alloc(sizeof(float) * (size_t)B_ * SPLITS * NSEQ);
  float*    Lp   = (float*)alloc(sizeof(float) * (size_t)B_ * SPLITS * NSEQ);
  float*    gsum = (float*)alloc(1024);
  float*    gsq  = (float*)alloc(1024);
  int*      flag = (int*)alloc(256);

  hipMemsetAsync(gsum, 0, 1024, stream);
  hipMemsetAsync(gsq, 0, 1024, stream);

  detect_k<<<1, 256, 0, stream>>>(d_in[0], flag);
  maxpool_k<<<4032, 256, 0, stream>>>(d_in[0], xp, flag);
  transpose_k<<<dim3(63, 4, B_), 256, 0, stream>>>((const u16*)xp, xpT, flag);
  qkv_mfma_k<<<dim3(63, 6, B_), 256, 0, stream>>>(xpT, d_in[1], d_in[2], d_in[3],
                                                  Qh, Ql, Kv, Vt, flag);
  qkv_vec_k<<<dim3(4, 24, B_), 256, 0, stream>>>((const float*)xp, d_in[1], d_in[2], d_in[3],
                                                 Qh, Ql, Kv, Vt, flag);
  flash_k<<<dim3(32, SPLITS, B_), 256, 0, stream>>>(Qh, Ql, Kv, Vt, big, Mp, Lp);
  merge_k<<<3969, 256, 0, stream>>>(big, Mp, Lp, Yb);
  out_k<<<dim3(4, 16, B_), 256, 0, stream>>>(Yb, d_in[4], big, gsum, gsq, flag);
  bn_k<<<(TOT + 255) / 256, 256, 0, stream>>>(big, gsum, gsq, d_in[5], d_in[6], xp, d_out, flag);
}